// Round 6
// baseline (219.581 us; speedup 1.0000x reference)
//
#include <hip/hip_runtime.h>

// CenterLoss: feature [B=128, D=128, T=2048] f32, label [B*T] int32, centers [64,128] f32
// out: [1 + 64*128] f32 = (loss, difference)
//
// R1-R3: ~180us pinned by 33.5M LDS float atomics. R5 (counting-sort gather, zero
// hot-loop atomics): k_main ~55-60us, 1 block/CU -> barrier/DMA stalls exposed.
// R6: 512 blocks (b x d-half x t-half) = 2 blocks/CU for cross-block overlap;
// 4 rows per barrier set (16 iters); wave-scan prefix; group-of-8 sort so all
// 256 threads gather 8 elements/row and all 256 are owners (c x 4 rows).

#define NT 2048
#define NC 64

// ws float offsets
#define OFF_P     0          // [512 blocks][64c * 64d] partial S
#define OFF_SSP   2097152    // [512] per-block sumsq
#define OFF_CNTP  2097664    // int [256 (b,th)][64 c]
#define OFF_CROSS 2114048    // [32]
#define OFF_CC    2114080    // [32]
#define OFF_SS    2114112    // [1]

// gfx9 s_waitcnt imm: vm[3:0]=bits3:0, exp=bits6:4, lgkm=bits11:8, vm[5:4]=bits15:14
#define WAIT_VM0()   __builtin_amdgcn_s_waitcnt(0x0F70)  // vmcnt(0), lgkm/exp free
#define WAIT_VM4()   __builtin_amdgcn_s_waitcnt(0x0F74)  // vmcnt(4)
#define WAIT_LGKM0() __builtin_amdgcn_s_waitcnt(0xC07F)  // lgkmcnt(0), vm/exp free
#define CFENCE()     __asm__ volatile("" ::: "memory")
#define BAR()        do { CFENCE(); __builtin_amdgcn_s_barrier(); CFENCE(); } while (0)

__device__ __forceinline__ void dma16(const float* g, float* l) {
    __builtin_amdgcn_global_load_lds(
        (const __attribute__((address_space(1))) void*)g,
        (__attribute__((address_space(3))) void*)l, 16, 0, 0);
}

__global__ __launch_bounds__(256) void k_main(const float* __restrict__ feat,
                                              const int*  __restrict__ label,
                                              float* __restrict__ ws) {
    __shared__ float rowbuf[2][4][1028];   // dbuf x 4 rows x (1024 data + zero slot @1024)
    __shared__ unsigned short __attribute__((aligned(16))) sorted[2048];
    __shared__ float S_lds[64][33];        // [c][d mod 32]
    __shared__ float partial[4][256];
    __shared__ int cnt[NC], pstart[NC], ntc[NC], cursor[NC];

    const int tid = threadIdx.x, bid = blockIdx.x;
    const int th = bid & 1, dh = (bid >> 1) & 1, b = bid >> 2;
    const int wave = tid >> 6, lane = tid & 63;

    // feature base for this block: rows d = dh*64 + [0,64), cols t = th*1024 + [0,1024)
    const float* fbase = feat + ((size_t)(b * 128 + dh * 64)) * NT + th * 1024;

    // ---- issue DMA for iteration 0 immediately (overlaps the sort prologue) ----
    // wave w stages row w: 4 chunks of 256 floats
    #pragma unroll
    for (int q = 0; q < 4; ++q)
        dma16(fbase + (size_t)wave * NT + q * 256 + lane * 4, &rowbuf[0][wave][q * 256]);

    // ---- init ----
    for (int j = tid; j < 2048; j += 256) sorted[j] = (unsigned short)4096;  // zero-slot byte off
    if (tid < NC) { cnt[tid] = 0; cursor[tid] = 0; }
    if (tid < 8) rowbuf[tid >> 2][tid & 3][1024] = 0.0f;
    __syncthreads();

    // ---- histogram: 1024 labels, 4 per thread ----
    const int* lp = label + b * NT + th * 1024 + tid * 4;
    const int4 L = *(const int4*)lp;
    atomicAdd(&cnt[L.x], 1); atomicAdd(&cnt[L.y], 1);
    atomicAdd(&cnt[L.z], 1); atomicAdd(&cnt[L.w], 1);
    __syncthreads();

    // ---- padded prefix via wave-64 scan (classes padded to x8) ----
    if (tid < 64) {
        const int pl = (cnt[tid] + 7) & ~7;
        int incl = pl;
        #pragma unroll
        for (int o = 1; o < 64; o <<= 1) {
            int n = __shfl_up(incl, o);
            if (tid >= o) incl += n;
        }
        pstart[tid] = incl - pl;      // total padded <= 1024 + 64*7 = 1472 <= 2048
        ntc[tid]    = pl >> 3;        // groups of 8
    }
    __syncthreads();

    if (dh == 0 && tid < NC) ((int*)(ws + OFF_CNTP))[(b * 2 + th) * NC + tid] = cnt[tid];

    // ---- scatter: sorted[pos] = byte offset of t within a 4KB row-half ----
    {
        const int t0 = tid * 4;
        int l, p;
        l = L.x; p = pstart[l] + atomicAdd(&cursor[l], 1); sorted[p] = (unsigned short)((t0 + 0) * 4);
        l = L.y; p = pstart[l] + atomicAdd(&cursor[l], 1); sorted[p] = (unsigned short)((t0 + 1) * 4);
        l = L.z; p = pstart[l] + atomicAdd(&cursor[l], 1); sorted[p] = (unsigned short)((t0 + 2) * 4);
        l = L.w; p = pstart[l] + atomicAdd(&cursor[l], 1); sorted[p] = (unsigned short)((t0 + 3) * 4);
    }
    __syncthreads();

    // ---- this thread's 8 permuted byte-offsets -> VGPRs (reused for all 64 rows) ----
    int off[8];
    {
        const uint4 pk = *(const uint4*)&sorted[tid * 8];
        off[0] = pk.x & 0xFFFF; off[1] = pk.x >> 16;
        off[2] = pk.y & 0xFFFF; off[3] = pk.y >> 16;
        off[4] = pk.z & 0xFFFF; off[5] = pk.z >> 16;
        off[6] = pk.w & 0xFFFF; off[7] = pk.w >> 16;
    }

    const int oc = tid & 63, orow = tid >> 6;          // owner assignment
    const int ft = pstart[oc] >> 3, on = ntc[oc];

    float ss = 0.0f;

    // ---- main loop: 16 iterations x 4 rows, double-buffered DMA ----
    for (int i = 0; i < 16; ++i) {
        const int buf = i & 1;
        if (i < 15) {
            const float* base = fbase + (size_t)(4 * (i + 1) + wave) * NT;
            #pragma unroll
            for (int q = 0; q < 4; ++q)
                dma16(base + q * 256 + lane * 4, &rowbuf[buf ^ 1][wave][q * 256]);
            WAIT_VM4();   // iter i's 4 chunks done; iter i+1's stay in flight
        } else {
            WAIT_VM0();
        }
        BAR();            // all waves' rows visible

        // gather + single-class register sums (zero atomics)
        #pragma unroll
        for (int r = 0; r < 4; ++r) {
            const char* rb = (const char*)&rowbuf[buf][r][0];
            float s = 0.0f;
            #pragma unroll
            for (int j = 0; j < 8; ++j) {
                float v = *(const float*)(rb + off[j]);
                s += v; ss += v * v;
            }
            partial[r][tid] = s;
        }
        WAIT_LGKM0();
        BAR();            // partials visible

        // owners: all 256 threads = (c 64) x (row 4)
        {
            float s = 0.0f;
            for (int j = 0; j < on; ++j) s += partial[orow][ft + j];
            S_lds[oc][(4 * i + orow) & 31] = s;
        }

        if ((i & 7) == 7) {  // flush 32-row tile, coalesced float4 stores
            WAIT_LGKM0();
            BAR();
            const int dbase = (i >> 3) << 5;
            const int c = tid >> 2, dj0 = (tid & 3) * 8;
            float4 v0, v1;
            v0.x = S_lds[c][dj0 + 0]; v0.y = S_lds[c][dj0 + 1];
            v0.z = S_lds[c][dj0 + 2]; v0.w = S_lds[c][dj0 + 3];
            v1.x = S_lds[c][dj0 + 4]; v1.y = S_lds[c][dj0 + 5];
            v1.z = S_lds[c][dj0 + 6]; v1.w = S_lds[c][dj0 + 7];
            float* dst = ws + OFF_P + (size_t)bid * 4096 + c * 64 + dbase + dj0;
            *(float4*)dst = v0;
            *(float4*)(dst + 4) = v1;
        }
    }

    // ---- block sumsq reduce ----
    __syncthreads();
    partial[0][tid] = ss;
    __syncthreads();
    for (int s = 128; s > 0; s >>= 1) {
        if (tid < s) partial[0][tid] += partial[0][tid + s];
        __syncthreads();
    }
    if (tid == 0) ws[OFF_SSP + bid] = partial[0][0];
}

__global__ __launch_bounds__(256) void k_red(float* __restrict__ ws,
                                             const float* __restrict__ centers,
                                             float* __restrict__ out) {
    const int tid = threadIdx.x, bid = blockIdx.x;

    if (bid == 32) {  // sumsq over 512 block partials
        __shared__ float r[256];
        r[tid] = ws[OFF_SSP + tid] + ws[OFF_SSP + 256 + tid];
        __syncthreads();
        for (int k = 128; k > 0; k >>= 1) { if (tid < k) r[tid] += r[tid + k]; __syncthreads(); }
        if (tid == 0) ws[OFF_SS] = r[0];
        return;
    }

    // counts: cnt[c] = sum over 256 (b,th) entries
    __shared__ int cred[256];
    __shared__ int cnt[NC];
    {
        const int c = tid & 63, part = tid >> 6;
        const int* cntP = (const int*)(ws + OFF_CNTP);
        int s = 0;
        for (int e2 = part * 64; e2 < part * 64 + 64; ++e2) s += cntP[e2 * NC + c];
        cred[tid] = s;
    }
    __syncthreads();
    if (tid < NC) cnt[tid] = cred[tid] + cred[tid + 64] + cred[tid + 128] + cred[tid + 192];
    __syncthreads();

    const int e = bid * 256 + tid;                 // (c,d)
    const int c = e >> 7, d = e & 127, dhh = d >> 6, dl = d & 63;
    // bid(b,dh,th) = b*4 + dh*2 + th ; sum over b(128), th(2)
    const float* Pp = ws + OFF_P + (size_t)(dhh * 2) * 4096 + c * 64 + dl;
    float sum = 0.0f;
    #pragma unroll 8
    for (int bb = 0; bb < 128; ++bb)
        sum += Pp[(size_t)bb * 16384] + Pp[(size_t)bb * 16384 + 4096];

    const float ctr = centers[e];
    const float cn  = (float)cnt[c];
    const float den = cn > 1.0f ? cn : 1.0f;
    out[1 + e] = (cn * ctr - sum) / den;

    __shared__ float r1[256], r2[256];
    r1[tid] = sum * ctr;
    r2[tid] = cn * ctr * ctr;
    __syncthreads();
    for (int k = 128; k > 0; k >>= 1) {
        if (tid < k) { r1[tid] += r1[tid + k]; r2[tid] += r2[tid + k]; }
        __syncthreads();
    }
    if (tid == 0) { ws[OFF_CROSS + bid] = r1[0]; ws[OFF_CC + bid] = r2[0]; }
}

__global__ __launch_bounds__(64) void k_epi(const float* __restrict__ ws,
                                            float* __restrict__ out) {
    int t = threadIdx.x;
    float cr = (t < 32) ? ws[OFF_CROSS + t] : 0.0f;
    float cc = (t < 32) ? ws[OFF_CC + t] : 0.0f;
    for (int o = 16; o > 0; o >>= 1) { cr += __shfl_down(cr, o); cc += __shfl_down(cc, o); }
    if (t == 0) out[0] = (ws[OFF_SS] - 2.0f * cr + cc) * (1.0f / 33554432.0f);
}

extern "C" void kernel_launch(void* const* d_in, const int* in_sizes, int n_in,
                              void* d_out, int out_size, void* d_ws, size_t ws_size,
                              hipStream_t stream) {
    const float* feat    = (const float*)d_in[0];
    const int*   label   = (const int*)d_in[1];
    const float* centers = (const float*)d_in[2];
    float* out = (float*)d_out;
    float* ws  = (float*)d_ws;

    hipLaunchKernelGGL(k_main, dim3(512), dim3(256), 0, stream, feat, label, ws);
    hipLaunchKernelGGL(k_red,  dim3(33),  dim3(256), 0, stream, ws, centers, out);
    hipLaunchKernelGGL(k_epi,  dim3(1),   dim3(64),  0, stream, ws, out);
}